// Round 11
// baseline (1002.976 us; speedup 1.0000x reference)
//
#include <hip/hip_runtime.h>
#include <cstdint>
#include <cstddef>

#define T_LEN 512
#define B_SZ  64
#define PH_T  64            // timesteps per phase
#define NPH   8
#define PHG_DW (2u*64u*PH_T*512u)   // G dwords per phase = 4,194,304

typedef _Float16 half2_t __attribute__((ext_vector_type(2)));

// fast activations: map to v_exp_f32; overflow-safe forms (inf -> exact 0/1)
__device__ __forceinline__ float sigf(float x) { return 1.0f / (1.0f + __expf(-x)); }
__device__ __forceinline__ float tanhfast(float x) {
    return 1.0f - 2.0f / (1.0f + __expf(2.0f * x));
}

__device__ __forceinline__ float dot2u(unsigned a, unsigned b, float c) {
#if defined(__has_builtin) && __has_builtin(__builtin_amdgcn_fdot2)
    return __builtin_amdgcn_fdot2(__builtin_bit_cast(half2_t, a),
                                  __builtin_bit_cast(half2_t, b), c, false);
#else
    union U { unsigned u; _Float16 h[2]; } ua, ub;
    ua.u = a; ub.u = b;
    return c + (float)ua.h[0] * (float)ub.h[0] + (float)ua.h[1] * (float)ub.h[1];
#endif
}

__device__ __forceinline__ int sdot4(unsigned a, unsigned b, int c) {
#if defined(__has_builtin) && __has_builtin(__builtin_amdgcn_sdot4)
    return __builtin_amdgcn_sdot4((int)a, (int)b, c, false);
#else
    int r = c;
#pragma unroll
    for (int i = 0; i < 4; ++i) {
        int av = (int)(signed char)((a >> (8 * i)) & 0xff);
        int bv = (int)(signed char)((b >> (8 * i)) & 0xff);
        r += av * bv;
    }
    return r;
#endif
}

__device__ __forceinline__ unsigned pkh(float x, float y) {
    union { _Float16 h[2]; unsigned u; } r;
    r.h[0] = (_Float16)x; r.h[1] = (_Float16)y;
    return r.u;
}
__device__ __forceinline__ float halfsel(unsigned g, int hi) {
    union { unsigned u; _Float16 h[2]; } r; r.u = g;
    return (float)r.h[hi];
}

// ---------------------------------------------------------------------------
// K_P: pack Wih f16 only. Layout: Wih_f at pk[262144..], Wih_b at pk[393216..].
// ---------------------------------------------------------------------------
__global__ void pack_w(const float* __restrict__ Wih_f, const float* __restrict__ Wih_b,
                       unsigned* __restrict__ pk)
{
    int o = blockIdx.x * 256 + threadIdx.x;     // 0..262143
    int j = o & 3, lane = (o >> 2) & 63, kpc = (o >> 8) & 31;
    int blk = (o >> 13) & 15, m = o >> 17;      // 0..1
    const float* W = m ? Wih_b : Wih_f;
    int row = blk * 64 + lane, k0 = kpc * 8 + j * 2;
    pk[262144 + o] = pkh(W[(size_t)row * 256 + k0], W[(size_t)row * 256 + k0 + 1]);
}

// ---------------------------------------------------------------------------
// K_A: per-row absmax of Whh (2048 rows). One wave per row.
// ---------------------------------------------------------------------------
__global__ void whh_amax(const float* __restrict__ Whh_f, const float* __restrict__ Whh_b,
                         float* __restrict__ amax)
{
    int row = blockIdx.x * 4 + (threadIdx.x >> 6);   // 0..2047
    int lane = threadIdx.x & 63;
    const float* W = (row < 1024) ? Whh_f : Whh_b;
    int r = row & 1023;
    float4 v = *(const float4*)(W + (size_t)r * 256 + lane * 4);
    float m = fmaxf(fmaxf(fabsf(v.x), fabsf(v.y)), fmaxf(fabsf(v.z), fabsf(v.w)));
#pragma unroll
    for (int s = 1; s < 64; s <<= 1) m = fmaxf(m, __shfl_xor(m, s, 64));
    if (lane == 0) amax[row] = fmaxf(m, 1e-12f);
}

// ---------------------------------------------------------------------------
// K_Q: quantize Whh -> int8; per-row dequant multiplier.
// ---------------------------------------------------------------------------
__global__ void pack_whh8(const float* __restrict__ Whh_f, const float* __restrict__ Whh_b,
                          const float* __restrict__ amax,
                          unsigned* __restrict__ q8, float* __restrict__ mrow)
{
    int o = blockIdx.x * 256 + threadIdx.x;     // 0..131071
    int j = o & 3, lane = (o >> 2) & 63, kpc = (o >> 8) & 15;
    int blk = (o >> 12) & 15, d = (o >> 16) & 1;
    int row = blk * 64 + lane, k0 = kpc * 16 + j * 4;
    const float* W = d ? Whh_b : Whh_f;
    float am = amax[d * 1024 + row];
    float s = 127.0f / am;
    unsigned out = 0;
#pragma unroll
    for (int i = 0; i < 4; ++i) {
        int q = (int)rintf(W[(size_t)row * 256 + k0 + i] * s);
        out |= ((unsigned)(q & 0xff)) << (8 * i);
    }
    q8[o] = out;
    if (kpc == 0 && j == 0)
        mrow[d * 1024 + row] = am * (1.0f / (127.0f * 127.0f));
}

// ---------------------------------------------------------------------------
// Fused phase kernel. grid 832 x 512.  (R9/R10 structure; this round:
// kpc 12..15 of the weights LDS-cached (66 KB, still 2 blocks/CU) to cut the
// per-step L2 weight stream 25% at UNCHANGED occupancy — the deconfounded
// stream-sensitivity test R7 couldn't give us)
//   blocks 0..127   : recurrence for phase lq
//   blocks 128..639 : input GEMM (f16) producing G for phase gq
//   blocks 640..767 : logit partials for phase logq (reads hout ring)
//   blocks 768..831 : Viterbi forward scan for phase vq (one block per b)
// ---------------------------------------------------------------------------
struct LstmS {
    uint4 wl[2][4][512];           // weight chunks kpc 12..15 (65536 B)
    unsigned char hbuf[2][256];    // int8 h, ping-pong (512 B)
};
struct GemmS { unsigned x2[32][128]; };            // 16 KB
struct LogS  { unsigned wout2[10][128]; };         // 5 KB
struct VitS  { float ls[64][10]; int bps[64][17]; };

__global__ __launch_bounds__(512, 2) void fused_phase(
    const unsigned* __restrict__ pk, const unsigned* __restrict__ q8,
    const float* __restrict__ mrow, unsigned* __restrict__ G,
    const float* __restrict__ W_out, float* __restrict__ state,
    float* __restrict__ lh, unsigned* __restrict__ hout,
    const int* __restrict__ sent, const float* __restrict__ emb,
    const float* __restrict__ b_f, const float* __restrict__ b_b,
    const float* __restrict__ b_out, const float* __restrict__ trans,
    float* __restrict__ tvit, unsigned long long* __restrict__ bp_pk,
    int lq, int gq, int logq, int vq)
{
    __shared__ __align__(16) char smem[66048];
    const int tid = threadIdx.x;

    if (blockIdx.x < 128) {
        // ================= recurrence =================
        if (lq < 0) return;
        LstmS& S = *(LstmS*)smem;
        const int cid = blockIdx.x;
        const int d = cid & 1, b = cid >> 1;
        const int l = tid & 63;
        const int w = tid >> 6;                  // wave 0..7
        const int c = w * 32 + (l >> 1);         // cell 0..255 (pair-shared)
        const int row0 = (l & 1) ? (256 + c) : c;    // gate row in [0,512)
        const int hi = c & 1;                    // f16 half within packed G dword

        const unsigned* w0p = q8 + ((size_t)(d * 16 +     (row0 >> 6)) * 16) * 256 + (row0 & 63) * 4;
        const unsigned* w1p = q8 + ((size_t)(d * 16 + 8 + (row0 >> 6)) * 16) * 256 + (row0 & 63) * 4;
        const float m0 = mrow[(size_t)d * 1024 + row0];
        const float m1 = mrow[(size_t)d * 1024 + 512 + row0];

        // LDS-cache kpc 12..15 (loaded once; read per step from LDS pipe)
#pragma unroll
        for (int k = 0; k < 4; ++k) {
            S.wl[0][k][tid] = *(const uint4*)(w0p + (12 + k) * 256);
            S.wl[1][k][tid] = *(const uint4*)(w1p + (12 + k) * 256);
        }

        uint4 wr0[12], wr1[12];                  // streamed kpc 0..11 (remat by compiler)
#pragma unroll
        for (int k = 0; k < 12; ++k) {
            wr0[k] = *(const uint4*)(w0p + k * 256);
            wr1[k] = *(const uint4*)(w1p + k * 256);
        }

        float cc = state[((size_t)cid * 2 + 0) * 256 + c];
        float hn = state[((size_t)cid * 2 + 1) * 256 + c];

        if (tid < 256) {
            float hh = state[((size_t)cid * 2 + 1) * 256 + tid];
            int q = (int)rintf(hh * 127.0f);
            S.hbuf[0][tid] = (unsigned char)(q & 0xff);
        }

        const unsigned* Gc = G + (size_t)(lq & 1) * PHG_DW
                               + ((size_t)(d * 64 + b)) * PH_T * 512;
        unsigned* Ho = hout + ((size_t)(lq & 1) * 128 + cid) * PH_T * 128;
        const int goff0 = row0 >> 1, goff1 = 256 + (row0 >> 1);
        __syncthreads();

        unsigned g0c = Gc[goff0], g1c = Gc[goff1];
        for (int t = 0; t < PH_T; ++t) {
            const int cur = t & 1;
            // prefetch next-step G; survives the raw (no-vmcnt) barrier
            const int tn = (t + 1 < PH_T) ? (t + 1) : t;
            unsigned g0n = Gc[(size_t)tn * 512 + goff0];
            unsigned g1n = Gc[(size_t)tn * 512 + goff1];
            const unsigned char* hc = S.hbuf[cur];

            // 4-way split accumulators (bit-exact reassociation)
            int a00 = 0, a01 = 0, a02 = 0, a03 = 0;
            int a10 = 0, a11 = 0, a12 = 0, a13 = 0;
            // streamed chunks kpc 0..11
#pragma unroll
            for (int k = 0; k < 12; k += 4) {
                uint4 h0 = *(const uint4*)(hc + (k + 0) * 16);
                uint4 h1 = *(const uint4*)(hc + (k + 1) * 16);
                uint4 h2 = *(const uint4*)(hc + (k + 2) * 16);
                uint4 h3 = *(const uint4*)(hc + (k + 3) * 16);
                a00 = sdot4(wr0[k+0].x, h0.x, a00); a00 = sdot4(wr0[k+0].y, h0.y, a00);
                a00 = sdot4(wr0[k+0].z, h0.z, a00); a00 = sdot4(wr0[k+0].w, h0.w, a00);
                a01 = sdot4(wr0[k+1].x, h1.x, a01); a01 = sdot4(wr0[k+1].y, h1.y, a01);
                a01 = sdot4(wr0[k+1].z, h1.z, a01); a01 = sdot4(wr0[k+1].w, h1.w, a01);
                a02 = sdot4(wr0[k+2].x, h2.x, a02); a02 = sdot4(wr0[k+2].y, h2.y, a02);
                a02 = sdot4(wr0[k+2].z, h2.z, a02); a02 = sdot4(wr0[k+2].w, h2.w, a02);
                a03 = sdot4(wr0[k+3].x, h3.x, a03); a03 = sdot4(wr0[k+3].y, h3.y, a03);
                a03 = sdot4(wr0[k+3].z, h3.z, a03); a03 = sdot4(wr0[k+3].w, h3.w, a03);
                a10 = sdot4(wr1[k+0].x, h0.x, a10); a10 = sdot4(wr1[k+0].y, h0.y, a10);
                a10 = sdot4(wr1[k+0].z, h0.z, a10); a10 = sdot4(wr1[k+0].w, h0.w, a10);
                a11 = sdot4(wr1[k+1].x, h1.x, a11); a11 = sdot4(wr1[k+1].y, h1.y, a11);
                a11 = sdot4(wr1[k+1].z, h1.z, a11); a11 = sdot4(wr1[k+1].w, h1.w, a11);
                a12 = sdot4(wr1[k+2].x, h2.x, a12); a12 = sdot4(wr1[k+2].y, h2.y, a12);
                a12 = sdot4(wr1[k+2].z, h2.z, a12); a12 = sdot4(wr1[k+2].w, h2.w, a12);
                a13 = sdot4(wr1[k+3].x, h3.x, a13); a13 = sdot4(wr1[k+3].y, h3.y, a13);
                a13 = sdot4(wr1[k+3].z, h3.z, a13); a13 = sdot4(wr1[k+3].w, h3.w, a13);
            }
            // cached chunks kpc 12..15 from LDS
            {
                uint4 h0 = *(const uint4*)(hc + 12 * 16);
                uint4 h1 = *(const uint4*)(hc + 13 * 16);
                uint4 h2 = *(const uint4*)(hc + 14 * 16);
                uint4 h3 = *(const uint4*)(hc + 15 * 16);
                uint4 c00 = S.wl[0][0][tid], c01 = S.wl[0][1][tid];
                uint4 c02 = S.wl[0][2][tid], c03 = S.wl[0][3][tid];
                uint4 c10 = S.wl[1][0][tid], c11 = S.wl[1][1][tid];
                uint4 c12 = S.wl[1][2][tid], c13 = S.wl[1][3][tid];
                a00 = sdot4(c00.x, h0.x, a00); a00 = sdot4(c00.y, h0.y, a00);
                a00 = sdot4(c00.z, h0.z, a00); a00 = sdot4(c00.w, h0.w, a00);
                a01 = sdot4(c01.x, h1.x, a01); a01 = sdot4(c01.y, h1.y, a01);
                a01 = sdot4(c01.z, h1.z, a01); a01 = sdot4(c01.w, h1.w, a01);
                a02 = sdot4(c02.x, h2.x, a02); a02 = sdot4(c02.y, h2.y, a02);
                a02 = sdot4(c02.z, h2.z, a02); a02 = sdot4(c02.w, h2.w, a02);
                a03 = sdot4(c03.x, h3.x, a03); a03 = sdot4(c03.y, h3.y, a03);
                a03 = sdot4(c03.z, h3.z, a03); a03 = sdot4(c03.w, h3.w, a03);
                a10 = sdot4(c10.x, h0.x, a10); a10 = sdot4(c10.y, h0.y, a10);
                a10 = sdot4(c10.z, h0.z, a10); a10 = sdot4(c10.w, h0.w, a10);
                a11 = sdot4(c11.x, h1.x, a11); a11 = sdot4(c11.y, h1.y, a11);
                a11 = sdot4(c11.z, h1.z, a11); a11 = sdot4(c11.w, h1.w, a11);
                a12 = sdot4(c12.x, h2.x, a12); a12 = sdot4(c12.y, h2.y, a12);
                a12 = sdot4(c12.z, h2.z, a12); a12 = sdot4(c12.w, h2.w, a12);
                a13 = sdot4(c13.x, h3.x, a13); a13 = sdot4(c13.y, h3.y, a13);
                a13 = sdot4(c13.z, h3.z, a13); a13 = sdot4(c13.w, h3.w, a13);
            }
            int i0 = (a00 + a01) + (a02 + a03);
            int i1 = (a10 + a11) + (a12 + a13);

            float a0 = (float)i0 * m0 + halfsel(g0c, hi);
            float a1 = (float)i1 * m1 + halfsel(g1c, hi);

            // in-wave gate exchange: pair (even,odd) = (i,g | f,o)
            float pa = __shfl_xor(a0, 1, 64);
            float pb = __shfl_xor(a1, 1, 64);
            float iv = (l & 1) ? pa : a0;
            float gg = (l & 1) ? pb : a1;
            float fv = (l & 1) ? a0 : pa;
            float ov = (l & 1) ? a1 : pb;
            cc = sigf(fv) * cc + sigf(iv) * tanhfast(gg);
            hn = sigf(ov) * tanhfast(cc);

            // bytewise h publish: owning (even) lane stores its cell directly
            int q = (int)rintf(hn * 127.0f);
            if (!(l & 1)) S.hbuf[cur ^ 1][c] = (unsigned char)(q & 0xff);

            // f16-pair h for logit blocks (off critical path)
            float hp2 = __shfl_xor(hn, 2, 64);
            if ((l & 3) == 0) Ho[(size_t)t * 128 + w * 16 + (l >> 2)] = pkh(hn, hp2);

            g0c = g0n; g1c = g1n;

            // raw barrier: LDS ordering only, no vmcnt drain
            asm volatile("s_waitcnt lgkmcnt(0)" ::: "memory");
            __builtin_amdgcn_sched_barrier(0);
            __builtin_amdgcn_s_barrier();
        }

        if (!(l & 1)) {
            state[((size_t)cid * 2 + 0) * 256 + c] = cc;
            state[((size_t)cid * 2 + 1) * 256 + c] = hn;
        }
    } else if (blockIdx.x < 640) {
        // ================= input GEMM for phase gq (f16) ==================
        if (gq < 0) return;
        GemmS& S = *(GemmS*)smem;
        int gid = blockIdx.x - 128;                 // 0..511
        int d = gid & 1, rq = (gid >> 1) & 1, tt = (gid >> 2) & 1, b = gid >> 3;
        const float* bv = d ? b_b : b_f;

        int ti = tid >> 4, seg = tid & 15;
        int tg  = gq * PH_T + tt * 32 + ti;
        int tin = d ? (511 - tg) : tg;
        int tok = sent[b * 512 + tin];
        {
            const float4* ep = (const float4*)(emb + (size_t)tok * 256 + seg * 16);
            float4 e0 = ep[0], e1 = ep[1], e2 = ep[2], e3 = ep[3];
            unsigned* xp = &S.x2[ti][seg * 8];
            xp[0] = pkh(e0.x, e0.y); xp[1] = pkh(e0.z, e0.w);
            xp[2] = pkh(e1.x, e1.y); xp[3] = pkh(e1.z, e1.w);
            xp[4] = pkh(e2.x, e2.y); xp[5] = pkh(e2.z, e2.w);
            xp[6] = pkh(e3.x, e3.y); xp[7] = pkh(e3.z, e3.w);
        }
        __syncthreads();

        int row = rq * 512 + tid;
        int blk = row >> 6, lane = tid & 63;
        const unsigned* wp = pk + (((size_t)(2 + d) * 16 + blk) * 32) * 256 + lane * 4;

        float bias = bv[row];
        float acc[32];
#pragma unroll
        for (int t = 0; t < 32; ++t) acc[t] = bias;

        for (int kpc = 0; kpc < 32; ++kpc) {
            uint4 w = *(const uint4*)(wp + kpc * 256);
#pragma unroll
            for (int t = 0; t < 32; ++t) {
                uint4 xv = *(const uint4*)&S.x2[t][kpc * 4];
                acc[t] = dot2u(w.x, xv.x, acc[t]);
                acc[t] = dot2u(w.y, xv.y, acc[t]);
                acc[t] = dot2u(w.z, xv.z, acc[t]);
                acc[t] = dot2u(w.w, xv.w, acc[t]);
            }
        }

        unsigned* Gg = G + (size_t)(gq & 1) * PHG_DW;
        size_t gbase = ((size_t)(d * 64 + b) * PH_T + tt * 32) * 512;
#pragma unroll
        for (int t = 0; t < 32; ++t) {
            float part = __shfl_xor(acc[t], 1, 64);
            if (!(tid & 1))
                Gg[gbase + (size_t)t * 512 + (row >> 1)] = pkh(acc[t], part);
        }
    } else if (blockIdx.x < 768) {
        // ================= logit partials for phase logq =================
        if (logq < 0) return;
        LogS& S = *(LogS*)smem;
        int cid = blockIdx.x - 640;                 // matches rec cid
        int d = cid & 1, b = cid >> 1;

        for (int i = tid; i < 1280; i += 512) {
            int k = i >> 7, dw = i & 127;
            S.wout2[k][dw] = pkh(W_out[(size_t)k * 512 + d * 256 + 2 * dw],
                                 W_out[(size_t)k * 512 + d * 256 + 2 * dw + 1]);
        }
        __syncthreads();

        int tt = tid >> 3, seg = tid & 7;
        const unsigned* Hp = hout + ((size_t)(logq & 1) * 128 + cid) * PH_T * 128
                                  + (size_t)tt * 128 + seg * 16;
        float acc[10];
#pragma unroll
        for (int k = 0; k < 10; ++k) acc[k] = 0.f;
#pragma unroll
        for (int c4 = 0; c4 < 4; ++c4) {
            uint4 hv = *(const uint4*)(Hp + c4 * 4);
#pragma unroll
            for (int k = 0; k < 10; ++k) {
                const unsigned* wq = &S.wout2[k][seg * 16 + c4 * 4];
                acc[k] = dot2u(hv.x, wq[0], acc[k]);
                acc[k] = dot2u(hv.y, wq[1], acc[k]);
                acc[k] = dot2u(hv.z, wq[2], acc[k]);
                acc[k] = dot2u(hv.w, wq[3], acc[k]);
            }
        }
#pragma unroll
        for (int k = 0; k < 10; ++k) {
            acc[k] += __shfl_xor(acc[k], 1, 64);
            acc[k] += __shfl_xor(acc[k], 2, 64);
            acc[k] += __shfl_xor(acc[k], 4, 64);
        }
        if (seg == 0) {
            int tg = logq * PH_T + tt;
            int t_in = d ? (511 - tg) : tg;
#pragma unroll
            for (int k = 0; k < 10; ++k)
                lh[((size_t)(d * 64 + b) * 512 + t_in) * 10 + k] = acc[k];
        }
    } else {
        // ================= Viterbi forward for phase vq =================
        if (vq < 0) return;
        VitS& S = *(VitS*)smem;
        const int b = blockIdx.x - 768;

        for (int i = tid; i < 640; i += 512) {
            int t = i / 10, k = i - t * 10;
            int tq = vq * PH_T + t;
            S.ls[t][k] = lh[((size_t)b * 512 + tq) * 10 + k]
                       + lh[((size_t)(64 + b) * 512 + tq) * 10 + k]
                       + b_out[k];
        }
        __syncthreads();
        if (tid >= 64) return;

        const int l = tid;
        const int jt = l & 15;
        const int ih = l >> 4;
        const int i0tab[4]  = {0, 3, 6, 8};
        const int cnttab[4] = {3, 3, 2, 2};
        const int i0 = i0tab[ih], cnt = cnttab[ih];
        const int jj = (jt < 10) ? jt : 9;
        float tr0 = trans[(i0 + 0) * 10 + jj];
        float tr1 = trans[(i0 + 1) * 10 + jj];
        float tr2 = trans[((cnt > 2) ? (i0 + 2) : 0) * 10 + jj];

        float v;
        int t0;
        if (vq == 0) { v = S.ls[0][jj]; t0 = 1; }
        else         { v = tvit[b * 16 + jj]; t0 = 0; }

        for (int t = t0; t < PH_T; ++t) {
            float p0 = __shfl(v, i0, 64);
            float p1 = __shfl(v, i0 + 1, 64);
            float p2 = __shfl(v, (cnt > 2) ? (i0 + 2) : i0, 64);
            float c0 = p0 + tr0;
            float c1 = p1 + tr1;
            float c2 = (cnt > 2) ? (p2 + tr2) : -3.0e30f;
            float best = c0; int arg = i0;
            if (c1 > best) { best = c1; arg = i0 + 1; }
            if (c2 > best) { best = c2; arg = i0 + 2; }
            float ob = __shfl_xor(best, 16, 64);
            int   oa = __shfl_xor(arg,  16, 64);
            bool tk = (ob > best) || (ob == best && (ih & 1));
            best = tk ? ob : best;  arg = tk ? oa : arg;
            float ob2 = __shfl_xor(best, 32, 64);
            int   oa2 = __shfl_xor(arg,  32, 64);
            bool tk2 = (ob2 > best) || (ob2 == best && ((ih >> 1) & 1));
            best = tk2 ? ob2 : best;  arg = tk2 ? oa2 : arg;
            if (l < 16) S.bps[t][l] = arg;
            v = S.ls[t][jj] + best;
        }
        if (l < 10) tvit[b * 16 + l] = v;

        unsigned long long w = 0;
#pragma unroll
        for (int q = 0; q < 10; ++q)
            w |= ((unsigned long long)(S.bps[l][q] & 15)) << (4 * q);
        bp_pk[(size_t)b * 512 + vq * PH_T + l] = w;
    }
}

// ---------------------------------------------------------------------------
// K_V final: forward scan for phase 7 only, then full backtrack from packed
// backpointers (phases 0..6 in ws, phase 7 local).
// ---------------------------------------------------------------------------
__global__ __launch_bounds__(64) void viterbi_final(
    const float* __restrict__ lh, const float* __restrict__ b_out,
    const float* __restrict__ trans, const float* __restrict__ tvit,
    const unsigned long long* __restrict__ bp_pk, float* __restrict__ out)
{
    int b = blockIdx.x;
    int l = threadIdx.x;
    __shared__ float ls[64][10];
    __shared__ int bps[64][17];

    for (int i = l; i < 640; i += 64) {
        int t = i / 10, k = i - t * 10;
        int tq = 448 + t;
        ls[t][k] = lh[((size_t)b * 512 + tq) * 10 + k]
                 + lh[((size_t)(64 + b) * 512 + tq) * 10 + k]
                 + b_out[k];
    }
    __syncthreads();

    const int jt = l & 15;
    const int ih = l >> 4;
    const int i0tab[4]  = {0, 3, 6, 8};
    const int cnttab[4] = {3, 3, 2, 2};
    const int i0 = i0tab[ih], cnt = cnttab[ih];
    const int jj = (jt < 10) ? jt : 9;
    float tr0 = trans[(i0 + 0) * 10 + jj];
    float tr1 = trans[(i0 + 1) * 10 + jj];
    float tr2 = trans[((cnt > 2) ? (i0 + 2) : 0) * 10 + jj];

    unsigned long long pkr[8];
#pragma unroll
    for (int c = 0; c < 7; ++c)
        pkr[c] = bp_pk[(size_t)b * 512 + c * 64 + l];

    float v = tvit[b * 16 + jj];
    for (int t = 0; t < 64; ++t) {
        float p0 = __shfl(v, i0, 64);
        float p1 = __shfl(v, i0 + 1, 64);
        float p2 = __shfl(v, (cnt > 2) ? (i0 + 2) : i0, 64);
        float c0 = p0 + tr0;
        float c1 = p1 + tr1;
        float c2 = (cnt > 2) ? (p2 + tr2) : -3.0e30f;
        float best = c0; int arg = i0;
        if (c1 > best) { best = c1; arg = i0 + 1; }
        if (c2 > best) { best = c2; arg = i0 + 2; }
        float ob = __shfl_xor(best, 16, 64);
        int   oa = __shfl_xor(arg,  16, 64);
        bool tk = (ob > best) || (ob == best && (ih & 1));
        best = tk ? ob : best;  arg = tk ? oa : arg;
        float ob2 = __shfl_xor(best, 32, 64);
        int   oa2 = __shfl_xor(arg,  32, 64);
        bool tk2 = (ob2 > best) || (ob2 == best && ((ih >> 1) & 1));
        best = tk2 ? ob2 : best;  arg = tk2 ? oa2 : arg;
        if (l < 16) bps[t][l] = arg;
        v = ls[t][jj] + best;
    }

    float best = -3.0e30f; int arg = 0;
#pragma unroll
    for (int i = 0; i < 10; ++i) {
        float ti = __shfl(v, i, 64);
        bool gt = ti > best;
        best = gt ? ti : best;
        arg  = gt ? i : arg;
    }
    __syncthreads();

    {
        unsigned long long w = 0;
#pragma unroll
        for (int q = 0; q < 10; ++q)
            w |= ((unsigned long long)(bps[l][q] & 15)) << (4 * q);
        pkr[7] = w;
    }

    int preg[8];
#pragma unroll
    for (int c = 0; c < 8; ++c) preg[c] = 0;
    int tag = arg;
    for (int t = 511; t >= 1; --t) {
        if (l == (t & 63)) preg[t >> 6] = tag;
        unsigned long long w = __shfl(pkr[t >> 6], t & 63, 64);
        tag = (int)((w >> (4 * tag)) & 15ull);
    }
    if (l == 0) { preg[0] = tag; out[b] = best; }

    float* po = out + 64 + (size_t)b * 512;
#pragma unroll
    for (int c = 0; c < 8; ++c) po[c * 64 + l] = (float)preg[c];
}

// ---------------------------------------------------------------------------
extern "C" void kernel_launch(void* const* d_in, const int* in_sizes, int n_in,
                              void* d_out, int out_size, void* d_ws, size_t ws_size,
                              hipStream_t stream)
{
    (void)in_sizes; (void)n_in; (void)out_size; (void)ws_size;
    const int*   sent  = (const int*)d_in[0];
    const float* emb   = (const float*)d_in[2];
    const float* Wih_f = (const float*)d_in[3];
    const float* Whh_f = (const float*)d_in[4];
    const float* b_f   = (const float*)d_in[5];
    const float* Wih_b = (const float*)d_in[6];
    const float* Whh_b = (const float*)d_in[7];
    const float* b_b   = (const float*)d_in[8];
    const float* W_out = (const float*)d_in[9];
    const float* b_out = (const float*)d_in[10];
    const float* trans = (const float*)d_in[11];
    float* out = (float*)d_out;

    char* ws = (char*)d_ws;
    unsigned* pk    = (unsigned*)ws;                        // 2 MB
    unsigned* G     = (unsigned*)(ws + 2097152u);           // 33.55 MB
    float*    lh    = (float*)(ws + 35651584u);             // 2.62 MB
    float*    state = (float*)(ws + 38273024u);             // 256 KB
    unsigned* q8    = (unsigned*)(ws + 38535168u);          // 512 KB
    float*    amax  = (float*)(ws + 39059456u);             // 8 KB
    float*    mrowp = (float*)(ws + 39067648u);             // 8 KB
    unsigned* hout  = (unsigned*)(ws + 39075840u);          // 8.39 MB
    float*    tvit  = (float*)(ws + 47464448u);             // 4 KB
    unsigned long long* bp_pk = (unsigned long long*)(ws + 47468544u); // 256 KB

    hipMemsetAsync(state, 0, (size_t)2 * 64 * 2 * 256 * 4, stream);

    hipLaunchKernelGGL(pack_w, dim3(1024), dim3(256), 0, stream,
                       Wih_f, Wih_b, pk);
    hipLaunchKernelGGL(whh_amax, dim3(512), dim3(256), 0, stream,
                       Whh_f, Whh_b, amax);
    hipLaunchKernelGGL(pack_whh8, dim3(512), dim3(256), 0, stream,
                       Whh_f, Whh_b, amax, q8, mrowp);

    // pipeline: launch running phase q also builds G(q+1), logits(q-1),
    // and Viterbi forward (q-2)
    hipLaunchKernelGGL(fused_phase, dim3(832), dim3(512), 0, stream,
                       pk, q8, mrowp, G, W_out, state, lh, hout,
                       sent, emb, b_f, b_b, b_out, trans, tvit, bp_pk,
                       -1, 0, -1, -1);
    for (int q = 0; q < NPH; ++q) {
        hipLaunchKernelGGL(fused_phase, dim3(832), dim3(512), 0, stream,
                           pk, q8, mrowp, G, W_out, state, lh, hout,
                           sent, emb, b_f, b_b, b_out, trans, tvit, bp_pk,
                           q, (q < NPH - 1) ? (q + 1) : -1, q - 1, q - 2);
    }
    hipLaunchKernelGGL(fused_phase, dim3(832), dim3(512), 0, stream,
                       pk, q8, mrowp, G, W_out, state, lh, hout,
                       sent, emb, b_f, b_b, b_out, trans, tvit, bp_pk,
                       -1, -1, NPH - 1, NPH - 2);

    hipLaunchKernelGGL(viterbi_final, dim3(64), dim3(64), 0, stream,
                       lh, b_out, trans, tvit, bp_pk, out);
}

// Round 14
// 971.300 us; speedup vs baseline: 1.0326x; 1.0326x over previous
//
#include <hip/hip_runtime.h>
#include <cstdint>
#include <cstddef>

#define T_LEN 512
#define B_SZ  64
#define PH_T  64            // timesteps per phase
#define NPH   8
#define PHG_DW (2u*64u*PH_T*512u)   // G dwords per phase = 4,194,304

typedef _Float16 half2_t __attribute__((ext_vector_type(2)));

// fast activations: map to v_exp_f32; overflow-safe forms (inf -> exact 0/1)
__device__ __forceinline__ float sigf(float x) { return 1.0f / (1.0f + __expf(-x)); }
__device__ __forceinline__ float tanhfast(float x) {
    return 1.0f - 2.0f / (1.0f + __expf(2.0f * x));
}

__device__ __forceinline__ float dot2u(unsigned a, unsigned b, float c) {
#if defined(__has_builtin) && __has_builtin(__builtin_amdgcn_fdot2)
    return __builtin_amdgcn_fdot2(__builtin_bit_cast(half2_t, a),
                                  __builtin_bit_cast(half2_t, b), c, false);
#else
    union U { unsigned u; _Float16 h[2]; } ua, ub;
    ua.u = a; ub.u = b;
    return c + (float)ua.h[0] * (float)ub.h[0] + (float)ua.h[1] * (float)ub.h[1];
#endif
}

__device__ __forceinline__ int sdot4(unsigned a, unsigned b, int c) {
#if defined(__has_builtin) && __has_builtin(__builtin_amdgcn_sdot4)
    return __builtin_amdgcn_sdot4((int)a, (int)b, c, false);
#else
    int r = c;
#pragma unroll
    for (int i = 0; i < 4; ++i) {
        int av = (int)(signed char)((a >> (8 * i)) & 0xff);
        int bv = (int)(signed char)((b >> (8 * i)) & 0xff);
        r += av * bv;
    }
    return r;
#endif
}

__device__ __forceinline__ unsigned pkh(float x, float y) {
    union { _Float16 h[2]; unsigned u; } r;
    r.h[0] = (_Float16)x; r.h[1] = (_Float16)y;
    return r.u;
}
__device__ __forceinline__ float halfsel(unsigned g, int hi) {
    union { unsigned u; _Float16 h[2]; } r; r.u = g;
    return (float)r.h[hi];
}

// ---------------------------------------------------------------------------
// K_P: pack Wih f16 only. Layout: Wih_f at pk[262144..], Wih_b at pk[393216..].
// ---------------------------------------------------------------------------
__global__ void pack_w(const float* __restrict__ Wih_f, const float* __restrict__ Wih_b,
                       unsigned* __restrict__ pk)
{
    int o = blockIdx.x * 256 + threadIdx.x;     // 0..262143
    int j = o & 3, lane = (o >> 2) & 63, kpc = (o >> 8) & 31;
    int blk = (o >> 13) & 15, m = o >> 17;      // 0..1
    const float* W = m ? Wih_b : Wih_f;
    int row = blk * 64 + lane, k0 = kpc * 8 + j * 2;
    pk[262144 + o] = pkh(W[(size_t)row * 256 + k0], W[(size_t)row * 256 + k0 + 1]);
}

// ---------------------------------------------------------------------------
// K_A: per-row absmax of Whh (2048 rows). One wave per row.
// ---------------------------------------------------------------------------
__global__ void whh_amax(const float* __restrict__ Whh_f, const float* __restrict__ Whh_b,
                         float* __restrict__ amax)
{
    int row = blockIdx.x * 4 + (threadIdx.x >> 6);   // 0..2047
    int lane = threadIdx.x & 63;
    const float* W = (row < 1024) ? Whh_f : Whh_b;
    int r = row & 1023;
    float4 v = *(const float4*)(W + (size_t)r * 256 + lane * 4);
    float m = fmaxf(fmaxf(fabsf(v.x), fabsf(v.y)), fmaxf(fabsf(v.z), fabsf(v.w)));
#pragma unroll
    for (int s = 1; s < 64; s <<= 1) m = fmaxf(m, __shfl_xor(m, s, 64));
    if (lane == 0) amax[row] = fmaxf(m, 1e-12f);
}

// ---------------------------------------------------------------------------
// K_Q: quantize Whh -> int8; per-row dequant multiplier.
// ---------------------------------------------------------------------------
__global__ void pack_whh8(const float* __restrict__ Whh_f, const float* __restrict__ Whh_b,
                          const float* __restrict__ amax,
                          unsigned* __restrict__ q8, float* __restrict__ mrow)
{
    int o = blockIdx.x * 256 + threadIdx.x;     // 0..131071
    int j = o & 3, lane = (o >> 2) & 63, kpc = (o >> 8) & 15;
    int blk = (o >> 12) & 15, d = (o >> 16) & 1;
    int row = blk * 64 + lane, k0 = kpc * 16 + j * 4;
    const float* W = d ? Whh_b : Whh_f;
    float am = amax[d * 1024 + row];
    float s = 127.0f / am;
    unsigned out = 0;
#pragma unroll
    for (int i = 0; i < 4; ++i) {
        int q = (int)rintf(W[(size_t)row * 256 + k0 + i] * s);
        out |= ((unsigned)(q & 0xff)) << (8 * i);
    }
    q8[o] = out;
    if (kpc == 0 && j == 0)
        mrow[d * 1024 + row] = am * (1.0f / (127.0f * 127.0f));
}

// ---------------------------------------------------------------------------
// Fused phase kernel. grid 832 x 512.  (R2 structure; critical-path trims:
// bytewise h publish, raw lgkmcnt-only step barrier, fast activations.
// Session's measured-best configuration: 993 us total, fused_phase 110.2 us,
// harness-verified in Round 9. Stream-cut (R8/R11) and chain-split +
// G-prefetch (R10) measured null-or-negative -> this structure's floor.)
//   blocks 0..127   : recurrence for phase lq
//   blocks 128..639 : input GEMM (f16) producing G for phase gq
//   blocks 640..767 : logit partials for phase logq (reads hout ring)
//   blocks 768..831 : Viterbi forward scan for phase vq (one block per b)
// ---------------------------------------------------------------------------
struct LstmS { unsigned char hbuf[2][256]; };      // int8 h, ping-pong (512 B)
struct GemmS { unsigned x2[32][128]; };            // 16 KB
struct LogS  { unsigned wout2[10][128]; };         // 5 KB
struct VitS  { float ls[64][10]; int bps[64][17]; };

__global__ __launch_bounds__(512, 2) void fused_phase(
    const unsigned* __restrict__ pk, const unsigned* __restrict__ q8,
    const float* __restrict__ mrow, unsigned* __restrict__ G,
    const float* __restrict__ W_out, float* __restrict__ state,
    float* __restrict__ lh, unsigned* __restrict__ hout,
    const int* __restrict__ sent, const float* __restrict__ emb,
    const float* __restrict__ b_f, const float* __restrict__ b_b,
    const float* __restrict__ b_out, const float* __restrict__ trans,
    float* __restrict__ tvit, unsigned long long* __restrict__ bp_pk,
    int lq, int gq, int logq, int vq)
{
    __shared__ __align__(16) char smem[16512];
    const int tid = threadIdx.x;

    if (blockIdx.x < 128) {
        // ================= recurrence =================
        if (lq < 0) return;
        LstmS& S = *(LstmS*)smem;
        const int cid = blockIdx.x;
        const int d = cid & 1, b = cid >> 1;
        const int l = tid & 63;
        const int w = tid >> 6;                  // wave 0..7
        const int c = w * 32 + (l >> 1);         // cell 0..255 (pair-shared)
        const int row0 = (l & 1) ? (256 + c) : c;    // gate row in [0,512)
        const int hi = c & 1;                    // f16 half within packed G dword

        const unsigned* w0p = q8 + ((size_t)(d * 16 +     (row0 >> 6)) * 16) * 256 + (row0 & 63) * 4;
        const unsigned* w1p = q8 + ((size_t)(d * 16 + 8 + (row0 >> 6)) * 16) * 256 + (row0 & 63) * 4;
        const float m0 = mrow[(size_t)d * 1024 + row0];
        const float m1 = mrow[(size_t)d * 1024 + 512 + row0];

        uint4 wr0[16], wr1[16];                  // streamed by compiler (R2 behavior)
#pragma unroll
        for (int k = 0; k < 16; ++k) {
            wr0[k] = *(const uint4*)(w0p + k * 256);
            wr1[k] = *(const uint4*)(w1p + k * 256);
        }

        float cc = state[((size_t)cid * 2 + 0) * 256 + c];
        float hn = state[((size_t)cid * 2 + 1) * 256 + c];

        if (tid < 256) {
            float hh = state[((size_t)cid * 2 + 1) * 256 + tid];
            int q = (int)rintf(hh * 127.0f);
            S.hbuf[0][tid] = (unsigned char)(q & 0xff);
        }

        const unsigned* Gc = G + (size_t)(lq & 1) * PHG_DW
                               + ((size_t)(d * 64 + b)) * PH_T * 512;
        unsigned* Ho = hout + ((size_t)(lq & 1) * 128 + cid) * PH_T * 128;
        __syncthreads();

        for (int t = 0; t < PH_T; ++t) {
            const int cur = t & 1;
            unsigned g0 = Gc[(size_t)t * 512 +       (row0 >> 1)];
            unsigned g1 = Gc[(size_t)t * 512 + 256 + (row0 >> 1)];
            const unsigned char* hc = S.hbuf[cur];

            int i0 = 0, i1 = 0;
#pragma unroll
            for (int k = 0; k < 16; ++k) {
                uint4 hp = *(const uint4*)(hc + k * 16);
                i0 = sdot4(wr0[k].x, hp.x, i0); i0 = sdot4(wr0[k].y, hp.y, i0);
                i0 = sdot4(wr0[k].z, hp.z, i0); i0 = sdot4(wr0[k].w, hp.w, i0);
                i1 = sdot4(wr1[k].x, hp.x, i1); i1 = sdot4(wr1[k].y, hp.y, i1);
                i1 = sdot4(wr1[k].z, hp.z, i1); i1 = sdot4(wr1[k].w, hp.w, i1);
            }
            float a0 = (float)i0 * m0 + halfsel(g0, hi);
            float a1 = (float)i1 * m1 + halfsel(g1, hi);

            // in-wave gate exchange: pair (even,odd) = (i,g | f,o)
            float pa = __shfl_xor(a0, 1, 64);
            float pb = __shfl_xor(a1, 1, 64);
            float iv = (l & 1) ? pa : a0;
            float gg = (l & 1) ? pb : a1;
            float fv = (l & 1) ? a0 : pa;
            float ov = (l & 1) ? a1 : pb;
            cc = sigf(fv) * cc + sigf(iv) * tanhfast(gg);
            hn = sigf(ov) * tanhfast(cc);

            // bytewise h publish: owning (even) lane stores its cell directly
            int q = (int)rintf(hn * 127.0f);
            if (!(l & 1)) S.hbuf[cur ^ 1][c] = (unsigned char)(q & 0xff);

            // f16-pair h for logit blocks (off critical path)
            float hp2 = __shfl_xor(hn, 2, 64);
            if ((l & 3) == 0) Ho[(size_t)t * 128 + w * 16 + (l >> 2)] = pkh(hn, hp2);

            // raw barrier: LDS ordering only, no vmcnt drain (Ho store and
            // weight loads stay in flight; G/weight uses get their own waits)
            asm volatile("s_waitcnt lgkmcnt(0)" ::: "memory");
            __builtin_amdgcn_sched_barrier(0);
            __builtin_amdgcn_s_barrier();
        }

        if (!(l & 1)) {
            state[((size_t)cid * 2 + 0) * 256 + c] = cc;
            state[((size_t)cid * 2 + 1) * 256 + c] = hn;
        }
    } else if (blockIdx.x < 640) {
        // ================= input GEMM for phase gq (f16) ==================
        if (gq < 0) return;
        GemmS& S = *(GemmS*)smem;
        int gid = blockIdx.x - 128;                 // 0..511
        int d = gid & 1, rq = (gid >> 1) & 1, tt = (gid >> 2) & 1, b = gid >> 3;
        const float* bv = d ? b_b : b_f;

        int ti = tid >> 4, seg = tid & 15;
        int tg  = gq * PH_T + tt * 32 + ti;
        int tin = d ? (511 - tg) : tg;
        int tok = sent[b * 512 + tin];
        {
            const float4* ep = (const float4*)(emb + (size_t)tok * 256 + seg * 16);
            float4 e0 = ep[0], e1 = ep[1], e2 = ep[2], e3 = ep[3];
            unsigned* xp = &S.x2[ti][seg * 8];
            xp[0] = pkh(e0.x, e0.y); xp[1] = pkh(e0.z, e0.w);
            xp[2] = pkh(e1.x, e1.y); xp[3] = pkh(e1.z, e1.w);
            xp[4] = pkh(e2.x, e2.y); xp[5] = pkh(e2.z, e2.w);
            xp[6] = pkh(e3.x, e3.y); xp[7] = pkh(e3.z, e3.w);
        }
        __syncthreads();

        int row = rq * 512 + tid;
        int blk = row >> 6, lane = tid & 63;
        const unsigned* wp = pk + (((size_t)(2 + d) * 16 + blk) * 32) * 256 + lane * 4;

        float bias = bv[row];
        float acc[32];
#pragma unroll
        for (int t = 0; t < 32; ++t) acc[t] = bias;

        for (int kpc = 0; kpc < 32; ++kpc) {
            uint4 w = *(const uint4*)(wp + kpc * 256);
#pragma unroll
            for (int t = 0; t < 32; ++t) {
                uint4 xv = *(const uint4*)&S.x2[t][kpc * 4];
                acc[t] = dot2u(w.x, xv.x, acc[t]);
                acc[t] = dot2u(w.y, xv.y, acc[t]);
                acc[t] = dot2u(w.z, xv.z, acc[t]);
                acc[t] = dot2u(w.w, xv.w, acc[t]);
            }
        }

        unsigned* Gg = G + (size_t)(gq & 1) * PHG_DW;
        size_t gbase = ((size_t)(d * 64 + b) * PH_T + tt * 32) * 512;
#pragma unroll
        for (int t = 0; t < 32; ++t) {
            float part = __shfl_xor(acc[t], 1, 64);
            if (!(tid & 1))
                Gg[gbase + (size_t)t * 512 + (row >> 1)] = pkh(acc[t], part);
        }
    } else if (blockIdx.x < 768) {
        // ================= logit partials for phase logq =================
        if (logq < 0) return;
        LogS& S = *(LogS*)smem;
        int cid = blockIdx.x - 640;                 // matches rec cid
        int d = cid & 1, b = cid >> 1;

        for (int i = tid; i < 1280; i += 512) {
            int k = i >> 7, dw = i & 127;
            S.wout2[k][dw] = pkh(W_out[(size_t)k * 512 + d * 256 + 2 * dw],
                                 W_out[(size_t)k * 512 + d * 256 + 2 * dw + 1]);
        }
        __syncthreads();

        int tt = tid >> 3, seg = tid & 7;
        const unsigned* Hp = hout + ((size_t)(logq & 1) * 128 + cid) * PH_T * 128
                                  + (size_t)tt * 128 + seg * 16;
        float acc[10];
#pragma unroll
        for (int k = 0; k < 10; ++k) acc[k] = 0.f;
#pragma unroll
        for (int c4 = 0; c4 < 4; ++c4) {
            uint4 hv = *(const uint4*)(Hp + c4 * 4);
#pragma unroll
            for (int k = 0; k < 10; ++k) {
                const unsigned* wq = &S.wout2[k][seg * 16 + c4 * 4];
                acc[k] = dot2u(hv.x, wq[0], acc[k]);
                acc[k] = dot2u(hv.y, wq[1], acc[k]);
                acc[k] = dot2u(hv.z, wq[2], acc[k]);
                acc[k] = dot2u(hv.w, wq[3], acc[k]);
            }
        }
#pragma unroll
        for (int k = 0; k < 10; ++k) {
            acc[k] += __shfl_xor(acc[k], 1, 64);
            acc[k] += __shfl_xor(acc[k], 2, 64);
            acc[k] += __shfl_xor(acc[k], 4, 64);
        }
        if (seg == 0) {
            int tg = logq * PH_T + tt;
            int t_in = d ? (511 - tg) : tg;
#pragma unroll
            for (int k = 0; k < 10; ++k)
                lh[((size_t)(d * 64 + b) * 512 + t_in) * 10 + k] = acc[k];
        }
    } else {
        // ================= Viterbi forward for phase vq =================
        if (vq < 0) return;
        VitS& S = *(VitS*)smem;
        const int b = blockIdx.x - 768;

        for (int i = tid; i < 640; i += 512) {
            int t = i / 10, k = i - t * 10;
            int tq = vq * PH_T + t;
            S.ls[t][k] = lh[((size_t)b * 512 + tq) * 10 + k]
                       + lh[((size_t)(64 + b) * 512 + tq) * 10 + k]
                       + b_out[k];
        }
        __syncthreads();
        if (tid >= 64) return;

        const int l = tid;
        const int jt = l & 15;
        const int ih = l >> 4;
        const int i0tab[4]  = {0, 3, 6, 8};
        const int cnttab[4] = {3, 3, 2, 2};
        const int i0 = i0tab[ih], cnt = cnttab[ih];
        const int jj = (jt < 10) ? jt : 9;
        float tr0 = trans[(i0 + 0) * 10 + jj];
        float tr1 = trans[(i0 + 1) * 10 + jj];
        float tr2 = trans[((cnt > 2) ? (i0 + 2) : 0) * 10 + jj];

        float v;
        int t0;
        if (vq == 0) { v = S.ls[0][jj]; t0 = 1; }
        else         { v = tvit[b * 16 + jj]; t0 = 0; }

        for (int t = t0; t < PH_T; ++t) {
            float p0 = __shfl(v, i0, 64);
            float p1 = __shfl(v, i0 + 1, 64);
            float p2 = __shfl(v, (cnt > 2) ? (i0 + 2) : i0, 64);
            float c0 = p0 + tr0;
            float c1 = p1 + tr1;
            float c2 = (cnt > 2) ? (p2 + tr2) : -3.0e30f;
            float best = c0; int arg = i0;
            if (c1 > best) { best = c1; arg = i0 + 1; }
            if (c2 > best) { best = c2; arg = i0 + 2; }
            float ob = __shfl_xor(best, 16, 64);
            int   oa = __shfl_xor(arg,  16, 64);
            bool tk = (ob > best) || (ob == best && (ih & 1));
            best = tk ? ob : best;  arg = tk ? oa : arg;
            float ob2 = __shfl_xor(best, 32, 64);
            int   oa2 = __shfl_xor(arg,  32, 64);
            bool tk2 = (ob2 > best) || (ob2 == best && ((ih >> 1) & 1));
            best = tk2 ? ob2 : best;  arg = tk2 ? oa2 : arg;
            if (l < 16) S.bps[t][l] = arg;
            v = S.ls[t][jj] + best;
        }
        if (l < 10) tvit[b * 16 + l] = v;

        unsigned long long w = 0;
#pragma unroll
        for (int q = 0; q < 10; ++q)
            w |= ((unsigned long long)(S.bps[l][q] & 15)) << (4 * q);
        bp_pk[(size_t)b * 512 + vq * PH_T + l] = w;
    }
}

// ---------------------------------------------------------------------------
// K_V final: forward scan for phase 7 only, then full backtrack from packed
// backpointers (phases 0..6 in ws, phase 7 local).
// ---------------------------------------------------------------------------
__global__ __launch_bounds__(64) void viterbi_final(
    const float* __restrict__ lh, const float* __restrict__ b_out,
    const float* __restrict__ trans, const float* __restrict__ tvit,
    const unsigned long long* __restrict__ bp_pk, float* __restrict__ out)
{
    int b = blockIdx.x;
    int l = threadIdx.x;
    __shared__ float ls[64][10];
    __shared__ int bps[64][17];

    for (int i = l; i < 640; i += 64) {
        int t = i / 10, k = i - t * 10;
        int tq = 448 + t;
        ls[t][k] = lh[((size_t)b * 512 + tq) * 10 + k]
                 + lh[((size_t)(64 + b) * 512 + tq) * 10 + k]
                 + b_out[k];
    }
    __syncthreads();

    const int jt = l & 15;
    const int ih = l >> 4;
    const int i0tab[4]  = {0, 3, 6, 8};
    const int cnttab[4] = {3, 3, 2, 2};
    const int i0 = i0tab[ih], cnt = cnttab[ih];
    const int jj = (jt < 10) ? jt : 9;
    float tr0 = trans[(i0 + 0) * 10 + jj];
    float tr1 = trans[(i0 + 1) * 10 + jj];
    float tr2 = trans[((cnt > 2) ? (i0 + 2) : 0) * 10 + jj];

    unsigned long long pkr[8];
#pragma unroll
    for (int c = 0; c < 7; ++c)
        pkr[c] = bp_pk[(size_t)b * 512 + c * 64 + l];

    float v = tvit[b * 16 + jj];
    for (int t = 0; t < 64; ++t) {
        float p0 = __shfl(v, i0, 64);
        float p1 = __shfl(v, i0 + 1, 64);
        float p2 = __shfl(v, (cnt > 2) ? (i0 + 2) : i0, 64);
        float c0 = p0 + tr0;
        float c1 = p1 + tr1;
        float c2 = (cnt > 2) ? (p2 + tr2) : -3.0e30f;
        float best = c0; int arg = i0;
        if (c1 > best) { best = c1; arg = i0 + 1; }
        if (c2 > best) { best = c2; arg = i0 + 2; }
        float ob = __shfl_xor(best, 16, 64);
        int   oa = __shfl_xor(arg,  16, 64);
        bool tk = (ob > best) || (ob == best && (ih & 1));
        best = tk ? ob : best;  arg = tk ? oa : arg;
        float ob2 = __shfl_xor(best, 32, 64);
        int   oa2 = __shfl_xor(arg,  32, 64);
        bool tk2 = (ob2 > best) || (ob2 == best && ((ih >> 1) & 1));
        best = tk2 ? ob2 : best;  arg = tk2 ? oa2 : arg;
        if (l < 16) bps[t][l] = arg;
        v = ls[t][jj] + best;
    }

    float best = -3.0e30f; int arg = 0;
#pragma unroll
    for (int i = 0; i < 10; ++i) {
        float ti = __shfl(v, i, 64);
        bool gt = ti > best;
        best = gt ? ti : best;
        arg  = gt ? i : arg;
    }
    __syncthreads();

    {
        unsigned long long w = 0;
#pragma unroll
        for (int q = 0; q < 10; ++q)
            w |= ((unsigned long long)(bps[l][q] & 15)) << (4 * q);
        pkr[7] = w;
    }

    int preg[8];
#pragma unroll
    for (int c = 0; c < 8; ++c) preg[c] = 0;
    int tag = arg;
    for (int t = 511; t >= 1; --t) {
        if (l == (t & 63)) preg[t >> 6] = tag;
        unsigned long long w = __shfl(pkr[t >> 6], t & 63, 64);
        tag = (int)((w >> (4 * tag)) & 15ull);
    }
    if (l == 0) { preg[0] = tag; out[b] = best; }

    float* po = out + 64 + (size_t)b * 512;
#pragma unroll
    for (int c = 0; c < 8; ++c) po[c * 64 + l] = (float)preg[c];
}

// ---------------------------------------------------------------------------
extern "C" void kernel_launch(void* const* d_in, const int* in_sizes, int n_in,
                              void* d_out, int out_size, void* d_ws, size_t ws_size,
                              hipStream_t stream)
{
    (void)in_sizes; (void)n_in; (void)out_size; (void)ws_size;
    const int*   sent  = (const int*)d_in[0];
    const float* emb   = (const float*)d_in[2];
    const float* Wih_f = (const float*)d_in[3];
    const float* Whh_f = (const float*)d_in[4];
    const float* b_f   = (const float*)d_in[5];
    const float* Wih_b = (const float*)d_in[6];
    const float* Whh_b = (const float*)d_in[7];
    const float* b_b   = (const float*)d_in[8];
    const float* W_out = (const float*)d_in[9];
    const float* b_out = (const float*)d_in[10];
    const float* trans = (const float*)d_in[11];
    float* out = (float*)d_out;

    char* ws = (char*)d_ws;
    unsigned* pk    = (unsigned*)ws;                        // 2 MB
    unsigned* G     = (unsigned*)(ws + 2097152u);           // 33.55 MB
    float*    lh    = (float*)(ws + 35651584u);             // 2.62 MB
    float*    state = (float*)(ws + 38273024u);             // 256 KB
    unsigned* q8    = (unsigned*)(ws + 38535168u);          // 512 KB
    float*    amax  = (float*)(ws + 39059456u);             // 8 KB
    float*    mrowp = (float*)(ws + 39067648u);             // 8 KB
    unsigned* hout  = (unsigned*)(ws + 39075840u);          // 8.39 MB
    float*    tvit  = (float*)(ws + 47464448u);             // 4 KB
    unsigned long long* bp_pk = (unsigned long long*)(ws + 47468544u); // 256 KB

    hipMemsetAsync(state, 0, (size_t)2 * 64 * 2 * 256 * 4, stream);

    hipLaunchKernelGGL(pack_w, dim3(1024), dim3(256), 0, stream,
                       Wih_f, Wih_b, pk);
    hipLaunchKernelGGL(whh_amax, dim3(512), dim3(256), 0, stream,
                       Whh_f, Whh_b, amax);
    hipLaunchKernelGGL(pack_whh8, dim3(512), dim3(256), 0, stream,
                       Whh_f, Whh_b, amax, q8, mrowp);

    // pipeline: launch running phase q also builds G(q+1), logits(q-1),
    // and Viterbi forward (q-2)
    hipLaunchKernelGGL(fused_phase, dim3(832), dim3(512), 0, stream,
                       pk, q8, mrowp, G, W_out, state, lh, hout,
                       sent, emb, b_f, b_b, b_out, trans, tvit, bp_pk,
                       -1, 0, -1, -1);
    for (int q = 0; q < NPH; ++q) {
        hipLaunchKernelGGL(fused_phase, dim3(832), dim3(512), 0, stream,
                           pk, q8, mrowp, G, W_out, state, lh, hout,
                           sent, emb, b_f, b_b, b_out, trans, tvit, bp_pk,
                           q, (q < NPH - 1) ? (q + 1) : -1, q - 1, q - 2);
    }
    hipLaunchKernelGGL(fused_phase, dim3(832), dim3(512), 0, stream,
                       pk, q8, mrowp, G, W_out, state, lh, hout,
                       sent, emb, b_f, b_b, b_out, trans, tvit, bp_pk,
                       -1, -1, NPH - 1, NPH - 2);

    hipLaunchKernelGGL(viterbi_final, dim3(64), dim3(64), 0, stream,
                       lh, b_out, trans, tvit, bp_pk, out);
}